// Round 2
// baseline (206.885 us; speedup 1.0000x reference)
//
#include <hip/hip_runtime.h>

#define N_RAYS    65536
#define N_SAMPLES 128

// 16 lanes per ray, 8 samples per lane, 4 rays per wave.
// weight[j] = max(sig_j - sig_{j+1}, 0) / sig_0 (telescoped transmittance),
// weight[0] = weight[127] = 0.
__global__ __launch_bounds__(256) void neus_render_kernel(
    const float4* __restrict__ sdf4,      // [R, S/4]
    const float4* __restrict__ color4,    // [R, S*3/4]
    const float4* __restrict__ z4,        // [R, S/4]
    const float*  __restrict__ s_ptr,     // [1]
    const float*  __restrict__ bg,        // [3]
    float* __restrict__ pixel_out,        // [R, 3]
    float* __restrict__ invdepth_out,     // [R]
    float4* __restrict__ weight4_out)     // [R, S/4]
{
    const int tid  = blockIdx.x * blockDim.x + threadIdx.x;
    const int lane = threadIdx.x & 63;
    const int sub  = lane & 15;            // lane position within its ray
    const int ray  = (tid >> 6) * 4 + (lane >> 4);

    const float s = s_ptr[0];

    const size_t rowq = (size_t)ray * (N_SAMPLES / 4);   // float4 index of row
    const int q0 = sub * 2;                              // first owned float4

    // ---- issue all loads up front (independent, coalesced float4) ----
    const float4 sd0 = sdf4[rowq + q0];
    const float4 sd1 = sdf4[rowq + q0 + 1];
    const float4 zz0 = z4[rowq + q0];
    const float4 zz1 = z4[rowq + q0 + 1];
    const size_t crowq = (size_t)ray * (N_SAMPLES * 3 / 4);
    float4 c[6];
    #pragma unroll
    for (int i = 0; i < 6; ++i) c[i] = color4[crowq + sub * 6 + i];

    // ---- sigmoids of the 8 owned samples ----
    float sg[8];
    {
        const float sdv[8] = {sd0.x, sd0.y, sd0.z, sd0.w,
                              sd1.x, sd1.y, sd1.z, sd1.w};
        #pragma unroll
        for (int k = 0; k < 8; ++k)
            sg[k] = __builtin_amdgcn_rcpf(1.0f + __expf(-sdv[k] * s));
    }

    // neighbor lane's first sigmoid = sample j0+8; ray's sample-0 sigmoid
    const float sig_nb    = __shfl_down(sg[0], 1);           // junk at sub==15 (unused)
    const float sig_first = __shfl(sg[0], lane & 48);        // lane 16*(lane>>4)
    const float inv0 = __builtin_amdgcn_rcpf(sig_first);

    // ---- weights ----
    float w[8];
    #pragma unroll
    for (int k = 0; k < 7; ++k) w[k] = fmaxf(sg[k] - sg[k + 1], 0.0f) * inv0;
    w[7] = fmaxf(sg[7] - sig_nb, 0.0f) * inv0;
    if (sub == 0)  w[0] = 0.0f;    // weight[0]   = 0
    if (sub == 15) w[7] = 0.0f;    // weight[127] = 0

    weight4_out[rowq + q0]     = make_float4(w[0], w[1], w[2], w[3]);
    weight4_out[rowq + q0 + 1] = make_float4(w[4], w[5], w[6], w[7]);

    // ---- per-lane partials ----
    const float zv[8] = {zz0.x, zz0.y, zz0.z, zz0.w,
                         zz1.x, zz1.y, zz1.z, zz1.w};
    const float* cf = (const float*)c;     // 24 consecutive floats: c[k][rgb]
    float pr = 0.f, pg = 0.f, pb = 0.f, invd = 0.f, wsum = 0.f;
    #pragma unroll
    for (int k = 0; k < 8; ++k) {
        invd += w[k] * __builtin_amdgcn_rcpf(zv[k]);
        pr   += w[k] * cf[3 * k + 0];
        pg   += w[k] * cf[3 * k + 1];
        pb   += w[k] * cf[3 * k + 2];
        wsum += w[k];
    }

    // ---- reduction across the 16 lanes of this ray (xor masks stay in-group) ----
    #pragma unroll
    for (int m = 8; m >= 1; m >>= 1) {
        pr   += __shfl_xor(pr, m);
        pg   += __shfl_xor(pg, m);
        pb   += __shfl_xor(pb, m);
        invd += __shfl_xor(invd, m);
        wsum += __shfl_xor(wsum, m);
    }

    if (sub == 0) {
        const float resid = 1.0f - wsum;
        pixel_out[ray * 3 + 0] = pr + resid * bg[0];
        pixel_out[ray * 3 + 1] = pg + resid * bg[1];
        pixel_out[ray * 3 + 2] = pb + resid * bg[2];
        invdepth_out[ray] = invd;
    }
}

extern "C" void kernel_launch(void* const* d_in, const int* in_sizes, int n_in,
                              void* d_out, int out_size, void* d_ws, size_t ws_size,
                              hipStream_t stream) {
    const float4* sdf   = (const float4*)d_in[0];
    const float4* color = (const float4*)d_in[1];
    const float4* z     = (const float4*)d_in[2];
    const float*  s     = (const float*)d_in[3];
    const float*  bg    = (const float*)d_in[4];

    float* out      = (float*)d_out;
    float* pixel    = out;                                  // [R,3]
    float* invdepth = out + (size_t)N_RAYS * 3;             // [R]
    float4* weight  = (float4*)(out + (size_t)N_RAYS * 3 + N_RAYS);  // [R,S]

    // 16 lanes per ray: 65536*16 threads -> 4096 blocks of 256
    const int block = 256;
    const int grid  = (N_RAYS * 16) / block;
    neus_render_kernel<<<grid, block, 0, stream>>>(
        sdf, color, z, s, bg, pixel, invdepth, weight);
}